// Round 3
// baseline (492.017 us; speedup 1.0000x reference)
//
#include <hip/hip_runtime.h>
#include <cmath>

// ---------------------------------------------------------------------------
// MLLA block, B=8 L=2048 C=512 H=8 HD=64 MLP_H=2048, fp32 I/O, bf16 MFMA GEMMs
// R10: gemm8 rebuilt on the counted-vmcnt 8-phase schedule (m201/T3+T4):
//      LDS [2buf][2 K-half][256][32] per operand, per-K-half XOR swizzle so
//      each 16KB half-tile is a linear global_load_lds target. 1 half-tile
//      staged per phase; vmcnt(8) at even-phase ends only (4-6 half-tiles in
//      flight, never drained to 0 in steady state; last iter peels 8/4/0).
//      Static buffer parity (buf0=even K-step, buf1=odd). Bit-identical acc.
// ---------------------------------------------------------------------------

typedef __bf16 bf16;
typedef __bf16 bf16x8 __attribute__((ext_vector_type(8)));
typedef __bf16 bf16x4 __attribute__((ext_vector_type(4)));
typedef float  f32x4  __attribute__((ext_vector_type(4)));

#define B_  8
#define L_  2048
#define C_  512
#define M_  (B_ * L_)          // 16384 tokens

__device__ __forceinline__ float fastrcp(float x) { return __builtin_amdgcn_rcpf(x); }

__device__ __forceinline__ float siluf(float x)
{
    return x * fastrcp(1.f + __expf(-x));
}
__device__ __forceinline__ float elu1f(float x) { return x > 0.f ? x + 1.f : __expf(x); }

// exact-GELU via Abramowitz-Stegun 7.1.25 erf (3-term, |eps| <= 2.5e-5)
__device__ __forceinline__ float geluf(float x)
{
    const float z = fabsf(x) * 0.70710678118654752f;
    const float t = fastrcp(__builtin_fmaf(z, 0.47047f, 1.f));
    const float poly = t * (0.3480242f + t * (-0.0958798f + t * 0.7478556f));
    const float erfz = __builtin_fmaf(-poly, __expf(-z * z), 1.f);
    const float hx = 0.5f * x;
    return __builtin_fmaf(hx, __builtin_copysignf(erfz, x), hx);
}

// global -> LDS direct DMA, 16B per lane. lds dest must be wave-uniform base;
// HW deposits lane i at base + i*16B. global source IS per-lane.
__device__ __forceinline__ void load_lds16(const bf16* g, bf16* l)
{
    __builtin_amdgcn_global_load_lds(
        (const __attribute__((address_space(1))) void*)g,
        (__attribute__((address_space(3))) void*)l, 16, 0, 0);
}

// ---------------------------------------------------------------------------
__global__ __launch_bounds__(256) void zero_k(float* __restrict__ p, int n)
{
    int i = blockIdx.x * 256 + threadIdx.x;
    if (i < n) p[i] = 0.f;
}

__global__ __launch_bounds__(64) void ws_diag_k(float* __restrict__ out, float v)
{
    if (threadIdx.x == 0 && blockIdx.x == 0) out[0] = v;
}

// ---------------------------------------------------------------------------
// fp32 -> bf16 elementwise (vectorized x4)
// ---------------------------------------------------------------------------
__global__ __launch_bounds__(256) void f32_to_bf16_k(
    const float* __restrict__ in, bf16* __restrict__ out, int n4)
{
    int i = blockIdx.x * 256 + threadIdx.x;
    if (i >= n4) return;
    float4 v = ((const float4*)in)[i];
    bf16x4 o = { (bf16)v.x, (bf16)v.y, (bf16)v.z, (bf16)v.w };
    ((bf16x4*)out)[i] = o;
}

// ---------------------------------------------------------------------------
// ALL weight transposes in one launch. fp32 (K x N) -> bf16 (N x K).
// ---------------------------------------------------------------------------
struct TJob  { const float* W; bf16* Wt; int K; int N; int blk0; };
struct TJobs { TJob j[7]; };

__global__ __launch_bounds__(256) void transpose_all_k(TJobs jobs)
{
    __shared__ float tile[32][33];
    const int bid = blockIdx.x;
    int ji = 0;
#pragma unroll
    for (int i = 1; i < 7; ++i) if (bid >= jobs.j[i].blk0) ji = i;
    const float* W  = jobs.j[ji].W;
    bf16*        Wt = jobs.j[ji].Wt;
    const int K = jobs.j[ji].K, N = jobs.j[ji].N;
    const int rel = bid - jobs.j[ji].blk0;
    const int nb = N >> 5;
    const int n0 = (rel % nb) * 32, k0 = (rel / nb) * 32;
    const int tx = threadIdx.x & 31, ty = threadIdx.x >> 5;   // 32 x 8
#pragma unroll
    for (int i = 0; i < 32; i += 8)
        tile[ty + i][tx] = W[(size_t)(k0 + ty + i) * N + n0 + tx];
    __syncthreads();
#pragma unroll
    for (int i = 0; i < 32; i += 8)
        Wt[(size_t)(n0 + ty + i) * K + k0 + tx] = (bf16)tile[tx][ty + i];
}

// ---------------------------------------------------------------------------
// depthwise conv (k=3, zero pad) along L + residual + LayerNorm.
// ---------------------------------------------------------------------------
__global__ __launch_bounds__(256) void cpe_ln_k(
    const float* __restrict__ xin, const float* __restrict__ cw,
    const float* __restrict__ cb, const float* __restrict__ g,
    const float* __restrict__ bb, float* __restrict__ xres,
    bf16* __restrict__ xln)
{
    const int token = blockIdx.x;
    const int l = token & (L_ - 1);
    const int tid = threadIdx.x;
    const float* row = xin + (size_t)token * C_;
    float v[2]; float s = 0.f, s2 = 0.f;
#pragma unroll
    for (int i = 0; i < 2; ++i) {
        const int c = tid + i * 256;
        float x0 = row[c];
        float xm = (l > 0)      ? row[c - C_] : 0.f;
        float xp = (l < L_ - 1) ? row[c + C_] : 0.f;
        float t = x0 + xm * cw[3*c] + x0 * cw[3*c+1] + xp * cw[3*c+2] + cb[c];
        v[i] = t; s += t; s2 += t * t;
    }
#pragma unroll
    for (int off = 32; off; off >>= 1) { s += __shfl_down(s, off); s2 += __shfl_down(s2, off); }
    __shared__ float rs[4], rs2[4];
    if ((tid & 63) == 0) { rs[tid >> 6] = s; rs2[tid >> 6] = s2; }
    __syncthreads();
    s  = rs[0] + rs[1] + rs[2] + rs[3];
    s2 = rs2[0] + rs2[1] + rs2[2] + rs2[3];
    const float mu = s * (1.f / C_);
    const float rstd = rsqrtf(s2 * (1.f / C_) - mu * mu + 1e-5f);
    float* orow = xres + (size_t)token * C_;
    bf16*  lrow = xln  + (size_t)token * C_;
#pragma unroll
    for (int i = 0; i < 2; ++i) {
        const int c = tid + i * 256;
        orow[c] = v[i];
        lrow[c] = (bf16)((v[i] - mu) * rstd * g[c] + bb[c]);
    }
}

// ---------------------------------------------------------------------------
// dwc conv over the (b,c,l)-reinterpreted flat buffer + SiLU.
// ---------------------------------------------------------------------------
__global__ __launch_bounds__(256) void dwc_silu_k(
    const bf16* __restrict__ Y, const float* __restrict__ w,
    const float* __restrict__ b, bf16* __restrict__ xp)
{
    const size_t idx = (size_t)blockIdx.x * 256 + threadIdx.x;   // over B_*L_*C_
    const int m = (int)(idx & (size_t)(L_ * C_ - 1));
    const int ch = m >> 11;          // m / 2048
    const int pos = m & (L_ - 1);
    float x0 = (float)Y[idx];
    float xm = (pos > 0)      ? (float)Y[idx - 1] : 0.f;
    float xq = (pos < L_ - 1) ? (float)Y[idx + 1] : 0.f;
    float t = xm * w[3*ch] + x0 * w[3*ch+1] + xq * w[3*ch+2] + b[ch];
    xp[idx] = (bf16)siluf(t);
}

// ---------------------------------------------------------------------------
// ksum[b, c] = sum_n k[b,n,c] from kvbT rows (c-major): contiguous reduction.
// ---------------------------------------------------------------------------
__global__ __launch_bounds__(256) void ksum_k(
    const bf16* __restrict__ kvbT, float* __restrict__ ksum)
{
    const int c = blockIdx.x;
    const int wave = threadIdx.x >> 6, lane = threadIdx.x & 63;
#pragma unroll
    for (int i = 0; i < 2; ++i) {
        const int b = wave + i * 4;
        const bf16* src = kvbT + (size_t)c * M_ + b * L_ + lane * 32;
        float s = 0.f;
#pragma unroll
        for (int u = 0; u < 4; ++u) {
            bf16x8 v = *(const bf16x8*)(src + u * 8);
#pragma unroll
            for (int j = 0; j < 8; ++j) s += (float)v[j];
        }
#pragma unroll
        for (int o = 32; o; o >>= 1) s += __shfl_down(s, o);
        if (lane == 0) ksum[b * C_ + c] = s;
    }
}

// ---------------------------------------------------------------------------
// kvpart[split][b,h,e,d] = sum_{n in split} v[b,n,h,e] * k[b,n,h,d]
// via MFMA (transposed layout [e][d]); plain stores, no atomics.
// ---------------------------------------------------------------------------
__global__ __launch_bounds__(256) void kvmat_mfma_k(
    const bf16* __restrict__ kvbT, float* __restrict__ kvpart)
{
    const int bh = blockIdx.x, b = bh >> 3, h = bh & 7;
    const int tid = threadIdx.x;
    const int wave = tid >> 6, lane = tid & 63;
    const int l16 = lane & 15, quad = lane >> 4;
    __shared__ bf16 As[64 * 72];   // vT chunk: [e][n]
    __shared__ bf16 Bs[64 * 72];   // kT chunk: [d][n]
    const int r = tid >> 2;              // 0..63: LDS row
    const int cseg = (tid & 3) * 16;     // 16 bf16 per thread
    const size_t kRow = (size_t)(h * 64 + r) * M_;
    const size_t vRow = (size_t)(512 + h * 64 + r) * M_;

    f32x4 acc[4];
    const f32x4 z4 = { 0.f, 0.f, 0.f, 0.f };
#pragma unroll
    for (int ni = 0; ni < 4; ++ni) acc[ni] = z4;

    for (int it = 0; it < 8; ++it) {
        const size_t colBase = (size_t)b * L_ + blockIdx.y * 512 + it * 64;
        {
            const bf16* ga = kvbT + vRow + colBase + cseg;   // A = v
            const bf16* gb = kvbT + kRow + colBase + cseg;   // B = k
            *(uint4*)&As[r * 72 + cseg]     = *(const uint4*)ga;
            *(uint4*)&As[r * 72 + cseg + 8] = *(const uint4*)(ga + 8);
            *(uint4*)&Bs[r * 72 + cseg]     = *(const uint4*)gb;
            *(uint4*)&Bs[r * 72 + cseg + 8] = *(const uint4*)(gb + 8);
        }
        __syncthreads();
#pragma unroll
        for (int kk = 0; kk < 64; kk += 32) {
            bf16x8 af = *(const bf16x8*)(&As[(wave * 16 + l16) * 72 + kk + quad * 8]);
#pragma unroll
            for (int ni = 0; ni < 4; ++ni) {
                bf16x8 bfr = *(const bf16x8*)(&Bs[(ni * 16 + l16) * 72 + kk + quad * 8]);
                acc[ni] = __builtin_amdgcn_mfma_f32_16x16x32_bf16(af, bfr, acc[ni], 0, 0, 0);
            }
        }
        __syncthreads();
    }
    float* dst = kvpart + (size_t)blockIdx.y * 262144 + (size_t)bh * 4096;  // [e][d]
#pragma unroll
    for (int ni = 0; ni < 4; ++ni)
#pragma unroll
        for (int rr = 0; rr < 4; ++rr)
            dst[(wave * 16 + quad * 4 + rr) * 64 + ni * 16 + l16] = acc[ni][rr];
}

// sum 4 partials, scale by 1/L, convert to bf16 (262144 elems)
__global__ __launch_bounds__(256) void kvconv_k(
    const float* __restrict__ p, bf16* __restrict__ out)
{
    int i = blockIdx.x * 256 + threadIdx.x;
    float s = p[i] + p[i + 262144] + p[i + 2 * 262144] + p[i + 3 * 262144];
    out[i] = (bf16)(s * (1.f / (float)L_));
}

// ---------------------------------------------------------------------------
// MFMA attention: per block (bh, 64-token tile); per wave 16 tokens.
// ---------------------------------------------------------------------------
__global__ __launch_bounds__(256) void attn_mfma_k(
    const bf16* __restrict__ q, const bf16* __restrict__ kvbT,
    const bf16* __restrict__ kvmatT, const float* __restrict__ ksum,
    const float* __restrict__ lw, const float* __restrict__ lb,
    const bf16* __restrict__ act_res, bf16* __restrict__ xa_mul)
{
    const int bh = blockIdx.x, b = bh >> 3, h = bh & 7;
    const int n0 = blockIdx.y * 64;
    const int tid = threadIdx.x;
    const int wave = tid >> 6, lane = tid & 63;
    const int l16 = lane & 15, quad = lane >> 4;

    __shared__ bf16 kvT[64 * 72];   // [e][d], stride 72 -> 2-way only
    __shared__ bf16 kmS[64];

#pragma unroll
    for (int i = 0; i < 2; ++i) {
        const int idx = i * 256 + tid;               // 512 chunks of 8
        const int row = idx >> 3, col = (idx & 7) * 8;
        *(bf16x8*)&kvT[row * 72 + col] =
            *(const bf16x8*)&kvmatT[(size_t)bh * 4096 + idx * 8];
    }
    if (tid < 64) kmS[tid] = (bf16)(ksum[b * C_ + h * 64 + tid] * (1.f / (float)L_));
    __syncthreads();

    // A-frags: 16 q-rows direct from global.
    const int tok = n0 + wave * 16;
    const bf16* qbase = q + ((size_t)b * L_ + tok) * C_ + h * 64;
    const bf16x8 af0 = *(const bf16x8*)(qbase + (size_t)l16 * C_ + quad * 8);
    const bf16x8 af1 = *(const bf16x8*)(qbase + (size_t)l16 * C_ + 32 + quad * 8);

    // z-dot: B-tile col0 = k_mean
    const bf16x8 z8 = { bf16(0.f), bf16(0.f), bf16(0.f), bf16(0.f),
                        bf16(0.f), bf16(0.f), bf16(0.f), bf16(0.f) };
    const bf16x8 km0 = *(const bf16x8*)&kmS[quad * 8];
    const bf16x8 km1 = *(const bf16x8*)&kmS[32 + quad * 8];
    const bf16x8 b20 = (l16 == 0) ? km0 : z8;
    const bf16x8 b21 = (l16 == 0) ? km1 : z8;
    f32x4 zd = { 0.f, 0.f, 0.f, 0.f };
    zd = __builtin_amdgcn_mfma_f32_16x16x32_bf16(af0, b20, zd, 0, 0, 0);
    zd = __builtin_amdgcn_mfma_f32_16x16x32_bf16(af1, b21, zd, 0, 0, 0);
    float zr[4];
#pragma unroll
    for (int r = 0; r < 4; ++r)
        zr[r] = fastrcp(__shfl(zd[r], (lane & 48)) + 1e-6f);

    // q @ kvmatT^T
    f32x4 acc[4];
    const f32x4 zf4 = { 0.f, 0.f, 0.f, 0.f };
#pragma unroll
    for (int ni = 0; ni < 4; ++ni) acc[ni] = zf4;
#pragma unroll
    for (int ni = 0; ni < 4; ++ni) {
        const bf16x8 b0 = *(const bf16x8*)&kvT[(ni * 16 + l16) * 72 + quad * 8];
        const bf16x8 b1 = *(const bf16x8*)&kvT[(ni * 16 + l16) * 72 + 32 + quad * 8];
        acc[ni] = __builtin_amdgcn_mfma_f32_16x16x32_bf16(af0, b0, acc[ni], 0, 0, 0);
        acc[ni] = __builtin_amdgcn_mfma_f32_16x16x32_bf16(af1, b1, acc[ni], 0, 0, 0);
    }

    // epilogue: lane holds (token = tok+quad*4+r, e = ni*16+l16)
#pragma unroll
    for (int ni = 0; ni < 4; ++ni) {
        const int e = ni * 16 + l16;
        const int c = h * 64 + e;
        const float w0 = lw[3*c], w1 = lw[3*c+1], w2 = lw[3*c+2], lbc = lb[c];
        const bf16* vrow = kvbT + (size_t)(512 + c) * M_ + b * L_;
#pragma unroll
        for (int r = 0; r < 4; ++r) {
            const int n = tok + quad * 4 + r;
            const float v0 = (float)vrow[n];
            const float vm = (n > 0)      ? (float)vrow[n - 1] : 0.f;
            const float vp = (n < L_ - 1) ? (float)vrow[n + 1] : 0.f;
            const float lepe = vm * w0 + v0 * w1 + vp * w2 + lbc;
            const float xa = acc[ni][r] * zr[r] + lepe;
            const size_t off = ((size_t)b * L_ + n) * C_ + c;
            xa_mul[off] = (bf16)(xa * (float)act_res[off]);
        }
    }
}

// ---------------------------------------------------------------------------
// bf16 MFMA GEMM, m97 structure + XOR-swizzled LDS tiles (128x128, 4 waves).
// Kept for N=512 shapes (q, out-proj, fc2).
// EPI: 2 elu+1->bf16, 4 gelu->bf16, 5 +res->f32, 7 kvT (row<512 elu)->bf16,
//      8 fused act/in: col<512 silu->outp, else plain->outp2
// ---------------------------------------------------------------------------
template <int EPI>
__global__ __launch_bounds__(256) void gemm_bt(
    const bf16* __restrict__ A, const bf16* __restrict__ Bt,
    const float* __restrict__ bias, const float* __restrict__ res,
    void* __restrict__ outp, void* __restrict__ outp2, int K, int N)
{
    __shared__ bf16 As[128 * 64];
    __shared__ bf16 Bs[128 * 64];
    const int tid = threadIdx.x;
    const int wave = tid >> 6, lane = tid & 63;
    const int wm = (wave & 1) * 64, wn = (wave >> 1) * 64;
    const int l16 = lane & 15, quad = lane >> 4;
    const size_t tileM = (size_t)blockIdx.x * 128;
    const size_t tileN = (size_t)blockIdx.y * 128;

    const int lrow = lane >> 3;
    const int lcol = (((lane & 7) ^ (lrow & 7))) * 8;   // swizzled source col
    const int swz  = l16 & 7;                           // read-side XOR

    const f32x4 z4 = { 0.f, 0.f, 0.f, 0.f };
    f32x4 acc[4][4];
#pragma unroll
    for (int mi = 0; mi < 4; ++mi)
#pragma unroll
        for (int ni = 0; ni < 4; ++ni) acc[mi][ni] = z4;

    for (int k0 = 0; k0 < K; k0 += 64) {
#pragma unroll
        for (int it = 0; it < 4; ++it) {
            const int rg = it * 32 + wave * 8;           // wave-uniform (mult of 8)
            load_lds16(A  + (tileM + rg + lrow) * (size_t)K + k0 + lcol, As + rg * 64);
            load_lds16(Bt + (tileN + rg + lrow) * (size_t)K + k0 + lcol, Bs + rg * 64);
        }
        __syncthreads();
#pragma unroll
        for (int kk = 0; kk < 64; kk += 32) {
            bf16x8 af[4], bfr[4];
#pragma unroll
            for (int mi = 0; mi < 4; ++mi)
                af[mi] = *(const bf16x8*)(&As[(wm + mi * 16 + l16) * 64
                                              + ((((kk >> 3) + quad) ^ swz) * 8)]);
#pragma unroll
            for (int ni = 0; ni < 4; ++ni)
                bfr[ni] = *(const bf16x8*)(&Bs[(wn + ni * 16 + l16) * 64
                                               + ((((kk >> 3) + quad) ^ swz) * 8)]);
#pragma unroll
            for (int mi = 0; mi < 4; ++mi)
#pragma unroll
                for (int ni = 0; ni < 4; ++ni)
                    acc[mi][ni] = __builtin_amdgcn_mfma_f32_16x16x32_bf16(
                        af[mi], bfr[ni], acc[mi][ni], 0, 0, 0);
        }
        __syncthreads();
    }

#pragma unroll
    for (int mi = 0; mi < 4; ++mi) {
#pragma unroll
        for (int ni = 0; ni < 4; ++ni) {
#pragma unroll
            for (int r = 0; r < 4; ++r) {
                const size_t row = tileM + wm + mi * 16 + quad * 4 + r;
                const int   col = (int)tileN + wn + ni * 16 + l16;
                float v = acc[mi][ni][r];
                const size_t oidx = row * (size_t)N + col;
                if (EPI == 2)      ((bf16*)outp)[oidx] = (bf16)elu1f(v + bias[col]);
                else if (EPI == 4) ((bf16*)outp)[oidx] = (bf16)geluf(v + bias[col]);
                else if (EPI == 5) ((float*)outp)[oidx] = v + bias[col] + res[oidx];
                else if (EPI == 7) {
                    v += bias[(int)row];
                    ((bf16*)outp)[oidx] = (bf16)((row < 512) ? elu1f(v) : v);
                } else if (EPI == 8) {
                    const size_t orow = row * (size_t)512;
                    if (col < 512) ((bf16*)outp )[orow + col]       = (bf16)siluf(v + bias[col]);
                    else           ((bf16*)outp2)[orow + col - 512] = (bf16)(v + res[col - 512]);
                }
            }
        }
    }
}

// ---------------------------------------------------------------------------
// 256x256 8-wave (2M x 4N) counted-vmcnt pipelined bf16 GEMM. BK=64 per
// K-step, processed as two 32-wide K-halves. LDS: [2 buf][2 kh][256 rows][32]
// per operand (buf0 = even K-steps, buf1 = odd; no pointer swap).
//
// Swizzle: logical 16B chunk c of row r stored at slot c ^ ((r>>1)&3) within
// the row's 64B; read addr mod 128 spans 8 distinct 16B slots / 16 lanes
// (same 2-lanes-per-slot structure as the proven 0-conflict R7 swizzle), and
// each (operand, K-half) half-tile (16KB) is LINEAR for global_load_lds.
//
// 8 phases per iteration (= 2 K-steps); per phase: {ds_read 4-8 x b128;
// stage 1 half-tile (2 x global_load_lds/wave); barrier; lgkmcnt(0);
// sched_barrier; setprio(1); 16 MFMA; setprio(0); [even ph: vmcnt]; barrier}.
//
// Stage schedule (iteration i): ph1 A(2i+1).kh1  ph2 B(2i+1).kh1 |vm8|
//   ph3 A(2i+2).kh0  ph4 B(2i+2).kh0 |vm8|  ph5 A(2i+2).kh1  ph6 B(2i+2).kh1
//   |vm8|  ph7 A(2i+3).kh0  ph8 B(2i+3).kh0 |vm8|.
// Each read's half-tile was staged 5-6 phases before the vmcnt that guards it;
// 4-6 half-tiles stay in flight (8-12 loads/wave), never drained to 0.
// Last iteration: stages ph3+ skipped; waits peel to vm8/vm4/vm0.
// Requires: M%256==0, N%256==0, K%128==0, K>=256.
// ---------------------------------------------------------------------------
template <int EPI>
__global__ __launch_bounds__(512, 2) void gemm8(
    const bf16* __restrict__ A, const bf16* __restrict__ Bt,
    const float* __restrict__ bias, const float* __restrict__ res,
    void* __restrict__ outp, void* __restrict__ outp2, int K, int N)
{
    __shared__ bf16 As[2][2][256 * 32];
    __shared__ bf16 Bs[2][2][256 * 32];
    const int tid  = threadIdx.x;
    const int wave = tid >> 6, lane = tid & 63;
    const int wrow = wave >> 2, wcol = wave & 3;       // 2 x 4 wave grid
    const int l16 = lane & 15, quad = lane >> 4;
    const size_t tileM = (size_t)blockIdx.x * 256;
    const size_t tileN = (size_t)blockIdx.y * 256;

    // staging: lane covers row (lane>>2) of its 16-row group, slot lane&3;
    // slot s of row r holds chunk c = s ^ ((r>>1)&3); group bases are
    // multiples of 16 so c = (lane&3) ^ ((lane>>3)&3).
    const int srow   = lane >> 2;
    const int schunk = ((lane & 3) ^ ((lane >> 3) & 3)) * 8;
    const bf16* aSrc = A  + (tileM + wave * 32 + srow) * (size_t)K + schunk;
    const bf16* bSrc = Bt + (tileN + wave * 32 + srow) * (size_t)K + schunk;

    // read-side slot permutation
    const int rperm = (quad ^ ((l16 >> 1) & 3)) * 8;

    f32x4 acc[8][4];
    const f32x4 z4 = { 0.f, 0.f, 0.f, 0.f };
#pragma unroll
    for (int mi = 0; mi < 8; ++mi)
#pragma unroll
        for (int ni = 0; ni < 4; ++ni) acc[mi][ni] = z4;

#define STAGE(SRC, DST, buf, s, kh) do {                                        \
    load_lds16(SRC + (size_t)(s) * 64 + (kh) * 32,                              \
               &DST[buf][kh][(wave * 32) * 32]);                                \
    load_lds16(SRC + (size_t)16 * K + (size_t)(s) * 64 + (kh) * 32,             \
               &DST[buf][kh][(wave * 32 + 16) * 32]);                           \
} while (0)
#define LDA(m, buf, kh, mi)                                                     \
    af[m] = *(const bf16x8*)&As[buf][kh][(wrow * 128 + (mi) * 16 + l16) * 32 + rperm]
#define LDB(n, buf, kh)                                                         \
    bfr[n] = *(const bf16x8*)&Bs[buf][kh][(wcol * 64 + (n) * 16 + l16) * 32 + rperm]
#define MFMA_Q(mo)                                                              \
    _Pragma("unroll") for (int m = 0; m < 4; ++m)                               \
    _Pragma("unroll") for (int n = 0; n < 4; ++n)                               \
        acc[(mo) + m][n] = __builtin_amdgcn_mfma_f32_16x16x32_bf16(             \
            af[m], bfr[n], acc[(mo) + m][n], 0, 0, 0)
#define PH_ENTER do { __builtin_amdgcn_s_barrier();                             \
    asm volatile("s_waitcnt lgkmcnt(0)" ::: "memory");                          \
    __builtin_amdgcn_sched_barrier(0);                                          \
    __builtin_amdgcn_s_setprio(1); } while (0)
#define PH_EXIT  do { __builtin_amdgcn_s_setprio(0);                            \
    __builtin_amdgcn_s_barrier(); } while (0)

    // prologue: stage step0 (buf0, kh0+kh1) and step1.kh0 (buf1) = 6 half-
    // tiles (12 loads/wave), in the steady-state "prev ph3..ph8" order.
    STAGE(aSrc, As, 0, 0, 0); STAGE(bSrc, Bs, 0, 0, 0);
    STAGE(aSrc, As, 0, 0, 1); STAGE(bSrc, Bs, 0, 0, 1);
    STAGE(aSrc, As, 1, 1, 0); STAGE(bSrc, Bs, 1, 1, 0);
    asm volatile("s_waitcnt vmcnt(8)" ::: "memory");   // step0.kh0 landed
    __builtin_amdgcn_s_barrier();

    const int NIT = K >> 7;                            // K/128 iterations
    for (int it = 0; it < NIT; ++it) {
        const bool lastI = (it == NIT - 1);
        const int s1 = 2 * it + 1, s2 = 2 * it + 2, s3 = 2 * it + 3;
        bf16x8 af[4], bfr[4];

        // ph1: Q0 x buf0.kh0 ; stage A(s1).kh1 -> buf1.kh1
        LDA(0, 0, 0, 0); LDA(1, 0, 0, 1); LDA(2, 0, 0, 2); LDA(3, 0, 0, 3);
        LDB(0, 0, 0);    LDB(1, 0, 0);    LDB(2, 0, 0);    LDB(3, 0, 0);
        STAGE(aSrc, As, 1, s1, 1);
        PH_ENTER; MFMA_Q(0); PH_EXIT;

        // ph2: Q1 x buf0.kh0 ; stage B(s1).kh1 ; vm8
        LDA(0, 0, 0, 4); LDA(1, 0, 0, 5); LDA(2, 0, 0, 6); LDA(3, 0, 0, 7);
        STAGE(bSrc, Bs, 1, s1, 1);
        PH_ENTER; MFMA_Q(4);
        __builtin_amdgcn_s_setprio(0);
        asm volatile("s_waitcnt vmcnt(8)" ::: "memory");
        __builtin_amdgcn_s_barrier();

        // ph3: Q0 x buf0.kh1 ; stage A(s2).kh0 -> buf0.kh0
        LDA(0, 0, 1, 0); LDA(1, 0, 1, 1); LDA(2, 0, 1, 2); LDA(3, 0, 1, 3);
        LDB(0, 0, 1);    LDB(1, 0, 1);    LDB(2, 0, 1);    LDB(3, 0, 1);
        if (!lastI) STAGE(aSrc, As, 0, s2, 0);
        PH_ENTER; MFMA_Q(0); PH_EXIT;

        // ph4: Q1 x buf0.kh1 ; stage B(s2).kh0 ; vm8 (last: vm4)
        LDA(0, 0, 1, 4); LDA(1, 0, 1, 5); LDA(2, 0, 1, 6); LDA(3, 0, 1, 7);
        if (!lastI) STAGE(bSrc, Bs, 0, s2, 0);
        PH_ENTER; MFMA_Q(4);
        __builtin_amdgcn_s_setprio(0);
        if (!lastI) { asm volatile("s_waitcnt vmcnt(8)" ::: "memory"); }
        else        { asm volatile("s_waitcnt vmcnt(4)" ::: "memory"); }
        __builtin_amdgcn_s_barrier();

        // ph5: Q0 x buf1.kh0 ; stage A(s2).kh1 -> buf0.kh1
        LDA(0, 1, 0, 0); LDA(1, 1, 0, 1); LDA(2, 1, 0, 2); LDA(3, 1, 0, 3);
        LDB(0, 1, 0);    LDB(1, 1, 0);    LDB(2, 1, 0);    LDB(3, 1, 0);
        if (!lastI) STAGE(aSrc, As, 0, s2, 1);
        PH_ENTER; MFMA_Q(0); PH_EXIT;

        // ph6: Q1 x buf1.kh0 ; stage B(s2).kh1 ; vm8 (last: vm0)
        LDA(0, 1, 0, 4); LDA(1, 1, 0, 5); LDA(2, 1, 0, 6); LDA(3, 1, 0, 7);
        if (!lastI) STAGE(bSrc, Bs, 0, s2, 1);
        PH_ENTER; MFMA_Q(4);
        __builtin_amdgcn_s_setprio(0);
        if (!lastI) { asm volatile("s_waitcnt vmcnt(8)" ::: "memory"); }
        else        { asm volatile("s_waitcnt vmcnt(0)" ::: "memory"); }
        __builtin_amdgcn_s_barrier();

        // ph7: Q0 x buf1.kh1 ; stage A(s3).kh0 -> buf1.kh0
        LDA(0, 1, 1, 0); LDA(1, 1, 1, 1); LDA(2, 1, 1, 2); LDA(3, 1, 1, 3);
        LDB(0, 1, 1);    LDB(1, 1, 1);    LDB(2, 1, 1);    LDB(3, 1, 1);
        if (!lastI) STAGE(aSrc, As, 1, s3, 0);
        PH_ENTER; MFMA_Q(0); PH_EXIT;

        // ph8: Q1 x buf1.kh1 ; stage B(s3).kh0 ; vm8 (last: none)
        LDA(0, 1, 1, 4); LDA(1, 1, 1, 5); LDA(2, 1, 1, 6); LDA(3, 1, 1, 7);
        if (!lastI) STAGE(bSrc, Bs, 1, s3, 0);
        PH_ENTER; MFMA_Q(4);
        __builtin_amdgcn_s_setprio(0);
        if (!lastI) { asm volatile("s_waitcnt vmcnt(8)" ::: "memory"); }
        __builtin_amdgcn_s_barrier();
    }
#undef STAGE
#undef LDA
#undef LDB
#undef MFMA_Q
#undef PH_ENTER
#undef PH_EXIT

    // epilogue: lane holds (row = tileM + wrow*128 + mi*16 + quad*4 + r,
    //                       col = tileN + wcol*64 + ni*16 + l16)
#pragma unroll
    for (int mi = 0; mi < 8; ++mi) {
#pragma unroll
        for (int ni = 0; ni < 4; ++ni) {
#pragma unroll
            for (int r = 0; r < 4; ++r) {
                const size_t row = tileM + wrow * 128 + mi * 16 + quad * 4 + r;
                const int   col = (int)tileN + wcol * 64 + ni * 16 + l16;
                float v = acc[mi][ni][r];
                const size_t oidx = row * (size_t)N + col;
                if (EPI == 2)      ((bf16*)outp)[oidx] = (bf16)elu1f(v + bias[col]);
                else if (EPI == 4) ((bf16*)outp)[oidx] = (bf16)geluf(v + bias[col]);
                else if (EPI == 5) ((float*)outp)[oidx] = v + bias[col] + res[oidx];
                else if (EPI == 7) {
                    v += bias[(int)row];
                    ((bf16*)outp)[oidx] = (bf16)((row < 512) ? elu1f(v) : v);
                } else if (EPI == 8) {
                    const size_t orow = row * (size_t)512;
                    if (col < 512) ((bf16*)outp )[orow + col]       = (bf16)siluf(v + bias[col]);
                    else           ((bf16*)outp2)[orow + col - 512] = (bf16)(v + res[col - 512]);
                }
            }
        }
    }
}

// ---------------------------------------------------------------------------
// workspace layout (bytes) — total 125,845,504 (~120 MiB)
// ---------------------------------------------------------------------------
#define OFF_WT_ACTIN ((size_t)0)         // bf16 [1024][512] 1MB
#define OFF_WT_Q    ((size_t)1048576)
#define OFF_WT_KV   ((size_t)1572864)
#define OFF_WT_OUT  ((size_t)2621440)
#define OFF_WT_FC1  ((size_t)3145728)
#define OFF_WT_FC2  ((size_t)5242880)
#define OFF_XLN     ((size_t)7340032)    // bf16 16MB (xqb, kvbf, hln alias)
#define OFF_ACTRES  ((size_t)24117248)   // bf16 16MB (x3 aliases from here)
#define OFF_Y       ((size_t)40894464)   // bf16 16MB (qb aliases)
#define OFF_XP      ((size_t)57671680)   // bf16 16MB (kvpart, h1 alias from here)
#define OFF_KV      ((size_t)74448896)   // bf16 32MB  kvbT [1024][16384]
#define OFF_KSUM    ((size_t)108003328)  // f32 16KB
#define OFF_XAMUL   ((size_t)109068288)  // bf16 16MB  -> end 125845504
#define OFF_X3      ((size_t)24117248)   // f32 32MB over actres+Y (dead)
#define OFF_H1      ((size_t)57671680)   // bf16 64MB over xp+kv+xamul (dead)
#define WS_REQUIRED ((size_t)125845504)

extern "C" void kernel_launch(void* const* d_in, const int* in_sizes, int n_in,
                              void* d_out, int out_size, void* d_ws, size_t ws_size,
                              hipStream_t stream)
{
    const float* x_q    = (const float*)d_in[0];
    const float* x_kv   = (const float*)d_in[1];
    const float* cpe1_w = (const float*)d_in[2];
    const float* cpe1_b = (const float*)d_in[3];
    const float* n1_g   = (const float*)d_in[4];
    const float* n1_b   = (const float*)d_in[5];
    const float* in_w   = (const float*)d_in[6];
    const float* in_b   = (const float*)d_in[7];
    const float* act_w  = (const float*)d_in[8];
    const float* act_b  = (const float*)d_in[9];
    const float* dwc_w  = (const float*)d_in[10];
    const float* dwc_b  = (const float*)d_in[11];
    const float* q_w    = (const float*)d_in[12];
    const float* q_b    = (const float*)d_in[13];
    const float* kv_w   = (const float*)d_in[14];
    const float* kv_b   = (const float*)d_in[15];
    const float* lepe_w = (const float*)d_in[16];
    const float* lepe_b = (const float*)d_in[17];
    const float* out_w  = (const float*)d_in[18];
    const float* out_b  = (const float*)d_in[19];
    const float* cpe2_w = (const float*)d_in[20];
    const float* cpe2_b = (const float*)d_in[21];
    const float* n2_g   = (const float*)d_in[22];
    const float* n2_b   = (const float*)d_in[23];
    const float* fc1_w  = (const float*)d_in[24];
    const float* fc1_b  = (const float*)d_in[25];
    const float* fc2_w  = (const float*)d_in[26];
    const float* fc2_b  = (const float*)d_in[27];

    float* outf = (float*)d_out;

    if (ws_size < WS_REQUIRED) {
        zero_k<<<(out_size + 255) / 256, 256, 0, stream>>>(outf, out_size);
        ws_diag_k<<<1, 64, 0, stream>>>(outf, (float)ws_size);
        return;
    }

    char* ws = (char*)d_ws;
    bf16*  wt_actin = (bf16*)(ws + OFF_WT_ACTIN);
    bf16*  wt_q   = (bf16*)(ws + OFF_WT_Q);
    bf16*  wt_kv  = (bf16*)(ws + OFF_WT_KV);
    bf16*  wt_out = (bf16*)(ws + OFF_WT_OUT);
    bf16*  wt_fc1 = (bf16*)(ws + OFF_WT_FC1);
    bf16*  wt_fc2 = (bf16*)(ws + OFF_WT_FC2);
    bf16*  xln    = (bf16*)(ws + OFF_XLN);
    bf16*  xqb    = (bf16*)(ws + OFF_XLN);      // alias: xln dead after act/in
    bf16*  kvbf   = (bf16*)(ws + OFF_XLN);      // alias: xqb dead after q-gemm
    bf16*  hln    = (bf16*)(ws + OFF_XLN);      // alias: kvbf dead after attn
    bf16*  actres = (bf16*)(ws + OFF_ACTRES);
    bf16*  Y      = (bf16*)(ws + OFF_Y);
    bf16*  qb     = (bf16*)(ws + OFF_Y);        // alias: Y dead after dwc
    bf16*  xp     = (bf16*)(ws + OFF_XP);
    float* kvpart = (float*)(ws + OFF_XP);      // alias: xp dead after kv-gemm (4MB)
    bf16*  kvbT   = (bf16*)(ws + OFF_KV);       // [1024][16384]
    float* ksum   = (float*)(ws + OFF_KSUM);
    bf16*  xamul  = (bf16*)(ws + OFF_XAMUL);
    float* x3     = (float*)(ws + OFF_X3);      // alias
    bf16*  h1     = (bf16*)(ws + OFF_H1);       // alias

    // all weight transposes in one launch
    TJobs jobs;
    jobs.j[0] = { act_w, wt_actin,             512,  512,    0 };
    jobs.j[1] = { in_w,  wt_actin + 512 * 512, 512,  512,  256 };
    jobs.j[2] = { q_w,   wt_q,                 512,  512,  512 };
    jobs.j[3] = { kv_w,  wt_kv,                512, 1024,  768 };
    jobs.j[4] = { out_w, wt_out,               512,  512, 1280 };
    jobs.j[5] = { fc1_w, wt_fc1,               512, 2048, 1536 };
    jobs.j[6] = { fc2_w, wt_fc2,              2048,  512, 2560 };
    transpose_all_k<<<3584, 256, 0, stream>>>(jobs);

    // cpe1 + LN1: shortcut (fp32) lives in d_out
    cpe_ln_k<<<M_, 256, 0, stream>>>(x_kv, cpe1_w, cpe1_b, n1_g, n1_b, outf, xln);

    // fused act gate + in-proj (one pass over xln), N=1024  [256x256 pipelined]
    gemm8<8><<<dim3(64, 4), 512, 0, stream>>>(xln, wt_actin, act_b, in_b, actres, Y, 512, 1024);

    // flat-reshape dwconv + silu -> xp (frees Y)
    dwc_silu_k<<<32768, 256, 0, stream>>>(Y, dwc_w, dwc_b, xp);

    // x_q -> bf16 (into dead xln region), then q = elu+1(xqb @ q_w) -> qb (@Y)
    f32_to_bf16_k<<<8192, 256, 0, stream>>>(x_q, xqb, M_ * C_ / 4);
    gemm_bt<2><<<dim3(128, 4), 256, 0, stream>>>(xqb, wt_q, q_b, nullptr, qb, nullptr, 512, 512);

    // kvbT[c][token] = (xp @ kv_w)^T : roles swapped (A=wt_kv, Bt=xp)  [256x256]
    gemm8<7><<<dim3(4, 64), 512, 0, stream>>>(wt_kv, xp, kv_b, nullptr, kvbT, nullptr, 512, M_);

    // k_mean, kvmatT partials (MFMA, no atomics), reduce+bf16 convert
    ksum_k<<<C_, 256, 0, stream>>>(kvbT, ksum);
    kvmat_mfma_k<<<dim3(64, 4), 256, 0, stream>>>(kvbT, kvpart);
    kvconv_k<<<1024, 256, 0, stream>>>(kvpart, kvbf);

    // MFMA attention + lepe + gate multiply
    attn_mfma_k<<<dim3(64, 32), 256, 0, stream>>>(qb, kvbT, kvbf, ksum,
                                                  lepe_w, lepe_b, actres, xamul);

    // out-proj + shortcut residual, in-place on d_out
    gemm_bt<5><<<dim3(128, 4), 256, 0, stream>>>(xamul, wt_out, out_b, outf, outf, nullptr, 512, 512);

    // cpe2 + LN2: x2 (=d_out) -> x3 (fp32 ws) + hln (bf16)
    cpe_ln_k<<<M_, 256, 0, stream>>>(outf, cpe2_w, cpe2_b, n2_g, n2_b, x3, hln);

    // MLP: fc1 (gelu) [256x256 pipelined] -> fc2 (+x3) -> d_out
    gemm8<4><<<dim3(64, 8), 512, 0, stream>>>(hln, wt_fc1, fc1_b, nullptr, h1, nullptr, 512, 2048);
    gemm_bt<5><<<dim3(128, 4),  256, 0, stream>>>(h1,  wt_fc2, fc2_b, x3, outf, nullptr, 2048, 512);

    (void)in_sizes; (void)n_in; (void)out_size; (void)ws_size;
}

// Round 4
// 469.320 us; speedup vs baseline: 1.0484x; 1.0484x over previous
//
#include <hip/hip_runtime.h>
#include <cmath>

// ---------------------------------------------------------------------------
// MLLA block, B=8 L=2048 C=512 H=8 HD=64 MLP_H=2048, fp32 I/O, bf16 MFMA GEMMs
// R11: gemm8 reverted to the R9 4-phase core (measured faster than R10's
//      counted-vmcnt at K=512). NEW: wide-store epilogues — wave-local LDS
//      transpose (reusing staging LDS after the final barrier) converts
//      128 scalar 2B stores/thread into 16 coalesced bf16x8 stores (and EPI5's
//      128 scalar f32 res loads into float4 loads). Bit-identical math.
// ---------------------------------------------------------------------------

typedef __bf16 bf16;
typedef __bf16 bf16x8 __attribute__((ext_vector_type(8)));
typedef __bf16 bf16x4 __attribute__((ext_vector_type(4)));
typedef float  f32x4  __attribute__((ext_vector_type(4)));

#define B_  8
#define L_  2048
#define C_  512
#define M_  (B_ * L_)          // 16384 tokens

__device__ __forceinline__ float fastrcp(float x) { return __builtin_amdgcn_rcpf(x); }

__device__ __forceinline__ float siluf(float x)
{
    return x * fastrcp(1.f + __expf(-x));
}
__device__ __forceinline__ float elu1f(float x) { return x > 0.f ? x + 1.f : __expf(x); }

// exact-GELU via Abramowitz-Stegun 7.1.25 erf (3-term, |eps| <= 2.5e-5)
__device__ __forceinline__ float geluf(float x)
{
    const float z = fabsf(x) * 0.70710678118654752f;
    const float t = fastrcp(__builtin_fmaf(z, 0.47047f, 1.f));
    const float poly = t * (0.3480242f + t * (-0.0958798f + t * 0.7478556f));
    const float erfz = __builtin_fmaf(-poly, __expf(-z * z), 1.f);
    const float hx = 0.5f * x;
    return __builtin_fmaf(hx, __builtin_copysignf(erfz, x), hx);
}

// global -> LDS direct DMA, 16B per lane. lds dest must be wave-uniform base;
// HW deposits lane i at base + i*16B.
__device__ __forceinline__ void load_lds16(const bf16* g, bf16* l)
{
    __builtin_amdgcn_global_load_lds(
        (const __attribute__((address_space(1))) void*)g,
        (__attribute__((address_space(3))) void*)l, 16, 0, 0);
}

// ---------------------------------------------------------------------------
__global__ __launch_bounds__(256) void zero_k(float* __restrict__ p, int n)
{
    int i = blockIdx.x * 256 + threadIdx.x;
    if (i < n) p[i] = 0.f;
}

__global__ __launch_bounds__(64) void ws_diag_k(float* __restrict__ out, float v)
{
    if (threadIdx.x == 0 && blockIdx.x == 0) out[0] = v;
}

// ---------------------------------------------------------------------------
// fp32 -> bf16 elementwise (vectorized x4)
// ---------------------------------------------------------------------------
__global__ __launch_bounds__(256) void f32_to_bf16_k(
    const float* __restrict__ in, bf16* __restrict__ out, int n4)
{
    int i = blockIdx.x * 256 + threadIdx.x;
    if (i >= n4) return;
    float4 v = ((const float4*)in)[i];
    bf16x4 o = { (bf16)v.x, (bf16)v.y, (bf16)v.z, (bf16)v.w };
    ((bf16x4*)out)[i] = o;
}

// ---------------------------------------------------------------------------
// ALL weight transposes in one launch. fp32 (K x N) -> bf16 (N x K).
// ---------------------------------------------------------------------------
struct TJob  { const float* W; bf16* Wt; int K; int N; int blk0; };
struct TJobs { TJob j[7]; };

__global__ __launch_bounds__(256) void transpose_all_k(TJobs jobs)
{
    __shared__ float tile[32][33];
    const int bid = blockIdx.x;
    int ji = 0;
#pragma unroll
    for (int i = 1; i < 7; ++i) if (bid >= jobs.j[i].blk0) ji = i;
    const float* W  = jobs.j[ji].W;
    bf16*        Wt = jobs.j[ji].Wt;
    const int K = jobs.j[ji].K, N = jobs.j[ji].N;
    const int rel = bid - jobs.j[ji].blk0;
    const int nb = N >> 5;
    const int n0 = (rel % nb) * 32, k0 = (rel / nb) * 32;
    const int tx = threadIdx.x & 31, ty = threadIdx.x >> 5;   // 32 x 8
#pragma unroll
    for (int i = 0; i < 32; i += 8)
        tile[ty + i][tx] = W[(size_t)(k0 + ty + i) * N + n0 + tx];
    __syncthreads();
#pragma unroll
    for (int i = 0; i < 32; i += 8)
        Wt[(size_t)(n0 + ty + i) * K + k0 + tx] = (bf16)tile[tx][ty + i];
}

// ---------------------------------------------------------------------------
// depthwise conv (k=3, zero pad) along L + residual + LayerNorm.
// ---------------------------------------------------------------------------
__global__ __launch_bounds__(256) void cpe_ln_k(
    const float* __restrict__ xin, const float* __restrict__ cw,
    const float* __restrict__ cb, const float* __restrict__ g,
    const float* __restrict__ bb, float* __restrict__ xres,
    bf16* __restrict__ xln)
{
    const int token = blockIdx.x;
    const int l = token & (L_ - 1);
    const int tid = threadIdx.x;
    const float* row = xin + (size_t)token * C_;
    float v[2]; float s = 0.f, s2 = 0.f;
#pragma unroll
    for (int i = 0; i < 2; ++i) {
        const int c = tid + i * 256;
        float x0 = row[c];
        float xm = (l > 0)      ? row[c - C_] : 0.f;
        float xp = (l < L_ - 1) ? row[c + C_] : 0.f;
        float t = x0 + xm * cw[3*c] + x0 * cw[3*c+1] + xp * cw[3*c+2] + cb[c];
        v[i] = t; s += t; s2 += t * t;
    }
#pragma unroll
    for (int off = 32; off; off >>= 1) { s += __shfl_down(s, off); s2 += __shfl_down(s2, off); }
    __shared__ float rs[4], rs2[4];
    if ((tid & 63) == 0) { rs[tid >> 6] = s; rs2[tid >> 6] = s2; }
    __syncthreads();
    s  = rs[0] + rs[1] + rs[2] + rs[3];
    s2 = rs2[0] + rs2[1] + rs2[2] + rs2[3];
    const float mu = s * (1.f / C_);
    const float rstd = rsqrtf(s2 * (1.f / C_) - mu * mu + 1e-5f);
    float* orow = xres + (size_t)token * C_;
    bf16*  lrow = xln  + (size_t)token * C_;
#pragma unroll
    for (int i = 0; i < 2; ++i) {
        const int c = tid + i * 256;
        orow[c] = v[i];
        lrow[c] = (bf16)((v[i] - mu) * rstd * g[c] + bb[c]);
    }
}

// ---------------------------------------------------------------------------
// dwc conv over the (b,c,l)-reinterpreted flat buffer + SiLU.
// ---------------------------------------------------------------------------
__global__ __launch_bounds__(256) void dwc_silu_k(
    const bf16* __restrict__ Y, const float* __restrict__ w,
    const float* __restrict__ b, bf16* __restrict__ xp)
{
    const size_t idx = (size_t)blockIdx.x * 256 + threadIdx.x;   // over B_*L_*C_
    const int m = (int)(idx & (size_t)(L_ * C_ - 1));
    const int ch = m >> 11;          // m / 2048
    const int pos = m & (L_ - 1);
    float x0 = (float)Y[idx];
    float xm = (pos > 0)      ? (float)Y[idx - 1] : 0.f;
    float xq = (pos < L_ - 1) ? (float)Y[idx + 1] : 0.f;
    float t = xm * w[3*ch] + x0 * w[3*ch+1] + xq * w[3*ch+2] + b[ch];
    xp[idx] = (bf16)siluf(t);
}

// ---------------------------------------------------------------------------
// ksum[b, c] = sum_n k[b,n,c] from kvbT rows (c-major): contiguous reduction.
// ---------------------------------------------------------------------------
__global__ __launch_bounds__(256) void ksum_k(
    const bf16* __restrict__ kvbT, float* __restrict__ ksum)
{
    const int c = blockIdx.x;
    const int wave = threadIdx.x >> 6, lane = threadIdx.x & 63;
#pragma unroll
    for (int i = 0; i < 2; ++i) {
        const int b = wave + i * 4;
        const bf16* src = kvbT + (size_t)c * M_ + b * L_ + lane * 32;
        float s = 0.f;
#pragma unroll
        for (int u = 0; u < 4; ++u) {
            bf16x8 v = *(const bf16x8*)(src + u * 8);
#pragma unroll
            for (int j = 0; j < 8; ++j) s += (float)v[j];
        }
#pragma unroll
        for (int o = 32; o; o >>= 1) s += __shfl_down(s, o);
        if (lane == 0) ksum[b * C_ + c] = s;
    }
}

// ---------------------------------------------------------------------------
// kvpart[split][b,h,e,d] = sum_{n in split} v[b,n,h,e] * k[b,n,h,d]
// via MFMA (transposed layout [e][d]); plain stores, no atomics.
// ---------------------------------------------------------------------------
__global__ __launch_bounds__(256) void kvmat_mfma_k(
    const bf16* __restrict__ kvbT, float* __restrict__ kvpart)
{
    const int bh = blockIdx.x, b = bh >> 3, h = bh & 7;
    const int tid = threadIdx.x;
    const int wave = tid >> 6, lane = tid & 63;
    const int l16 = lane & 15, quad = lane >> 4;
    __shared__ bf16 As[64 * 72];   // vT chunk: [e][n]
    __shared__ bf16 Bs[64 * 72];   // kT chunk: [d][n]
    const int r = tid >> 2;              // 0..63: LDS row
    const int cseg = (tid & 3) * 16;     // 16 bf16 per thread
    const size_t kRow = (size_t)(h * 64 + r) * M_;
    const size_t vRow = (size_t)(512 + h * 64 + r) * M_;

    f32x4 acc[4];
    const f32x4 z4 = { 0.f, 0.f, 0.f, 0.f };
#pragma unroll
    for (int ni = 0; ni < 4; ++ni) acc[ni] = z4;

    for (int it = 0; it < 8; ++it) {
        const size_t colBase = (size_t)b * L_ + blockIdx.y * 512 + it * 64;
        {
            const bf16* ga = kvbT + vRow + colBase + cseg;   // A = v
            const bf16* gb = kvbT + kRow + colBase + cseg;   // B = k
            *(uint4*)&As[r * 72 + cseg]     = *(const uint4*)ga;
            *(uint4*)&As[r * 72 + cseg + 8] = *(const uint4*)(ga + 8);
            *(uint4*)&Bs[r * 72 + cseg]     = *(const uint4*)gb;
            *(uint4*)&Bs[r * 72 + cseg + 8] = *(const uint4*)(gb + 8);
        }
        __syncthreads();
#pragma unroll
        for (int kk = 0; kk < 64; kk += 32) {
            bf16x8 af = *(const bf16x8*)(&As[(wave * 16 + l16) * 72 + kk + quad * 8]);
#pragma unroll
            for (int ni = 0; ni < 4; ++ni) {
                bf16x8 bfr = *(const bf16x8*)(&Bs[(ni * 16 + l16) * 72 + kk + quad * 8]);
                acc[ni] = __builtin_amdgcn_mfma_f32_16x16x32_bf16(af, bfr, acc[ni], 0, 0, 0);
            }
        }
        __syncthreads();
    }
    float* dst = kvpart + (size_t)blockIdx.y * 262144 + (size_t)bh * 4096;  // [e][d]
#pragma unroll
    for (int ni = 0; ni < 4; ++ni)
#pragma unroll
        for (int rr = 0; rr < 4; ++rr)
            dst[(wave * 16 + quad * 4 + rr) * 64 + ni * 16 + l16] = acc[ni][rr];
}

// sum 4 partials, scale by 1/L, convert to bf16 (262144 elems)
__global__ __launch_bounds__(256) void kvconv_k(
    const float* __restrict__ p, bf16* __restrict__ out)
{
    int i = blockIdx.x * 256 + threadIdx.x;
    float s = p[i] + p[i + 262144] + p[i + 2 * 262144] + p[i + 3 * 262144];
    out[i] = (bf16)(s * (1.f / (float)L_));
}

// ---------------------------------------------------------------------------
// MFMA attention: per block (bh, 64-token tile); per wave 16 tokens.
// ---------------------------------------------------------------------------
__global__ __launch_bounds__(256) void attn_mfma_k(
    const bf16* __restrict__ q, const bf16* __restrict__ kvbT,
    const bf16* __restrict__ kvmatT, const float* __restrict__ ksum,
    const float* __restrict__ lw, const float* __restrict__ lb,
    const bf16* __restrict__ act_res, bf16* __restrict__ xa_mul)
{
    const int bh = blockIdx.x, b = bh >> 3, h = bh & 7;
    const int n0 = blockIdx.y * 64;
    const int tid = threadIdx.x;
    const int wave = tid >> 6, lane = tid & 63;
    const int l16 = lane & 15, quad = lane >> 4;

    __shared__ bf16 kvT[64 * 72];   // [e][d], stride 72 -> 2-way only
    __shared__ bf16 kmS[64];

#pragma unroll
    for (int i = 0; i < 2; ++i) {
        const int idx = i * 256 + tid;               // 512 chunks of 8
        const int row = idx >> 3, col = (idx & 7) * 8;
        *(bf16x8*)&kvT[row * 72 + col] =
            *(const bf16x8*)&kvmatT[(size_t)bh * 4096 + idx * 8];
    }
    if (tid < 64) kmS[tid] = (bf16)(ksum[b * C_ + h * 64 + tid] * (1.f / (float)L_));
    __syncthreads();

    // A-frags: 16 q-rows direct from global.
    const int tok = n0 + wave * 16;
    const bf16* qbase = q + ((size_t)b * L_ + tok) * C_ + h * 64;
    const bf16x8 af0 = *(const bf16x8*)(qbase + (size_t)l16 * C_ + quad * 8);
    const bf16x8 af1 = *(const bf16x8*)(qbase + (size_t)l16 * C_ + 32 + quad * 8);

    // z-dot: B-tile col0 = k_mean
    const bf16x8 z8 = { bf16(0.f), bf16(0.f), bf16(0.f), bf16(0.f),
                        bf16(0.f), bf16(0.f), bf16(0.f), bf16(0.f) };
    const bf16x8 km0 = *(const bf16x8*)&kmS[quad * 8];
    const bf16x8 km1 = *(const bf16x8*)&kmS[32 + quad * 8];
    const bf16x8 b20 = (l16 == 0) ? km0 : z8;
    const bf16x8 b21 = (l16 == 0) ? km1 : z8;
    f32x4 zd = { 0.f, 0.f, 0.f, 0.f };
    zd = __builtin_amdgcn_mfma_f32_16x16x32_bf16(af0, b20, zd, 0, 0, 0);
    zd = __builtin_amdgcn_mfma_f32_16x16x32_bf16(af1, b21, zd, 0, 0, 0);
    float zr[4];
#pragma unroll
    for (int r = 0; r < 4; ++r)
        zr[r] = fastrcp(__shfl(zd[r], (lane & 48)) + 1e-6f);

    // q @ kvmatT^T
    f32x4 acc[4];
    const f32x4 zf4 = { 0.f, 0.f, 0.f, 0.f };
#pragma unroll
    for (int ni = 0; ni < 4; ++ni) acc[ni] = zf4;
#pragma unroll
    for (int ni = 0; ni < 4; ++ni) {
        const bf16x8 b0 = *(const bf16x8*)&kvT[(ni * 16 + l16) * 72 + quad * 8];
        const bf16x8 b1 = *(const bf16x8*)&kvT[(ni * 16 + l16) * 72 + 32 + quad * 8];
        acc[ni] = __builtin_amdgcn_mfma_f32_16x16x32_bf16(af0, b0, acc[ni], 0, 0, 0);
        acc[ni] = __builtin_amdgcn_mfma_f32_16x16x32_bf16(af1, b1, acc[ni], 0, 0, 0);
    }

    // epilogue: lane holds (token = tok+quad*4+r, e = ni*16+l16)
#pragma unroll
    for (int ni = 0; ni < 4; ++ni) {
        const int e = ni * 16 + l16;
        const int c = h * 64 + e;
        const float w0 = lw[3*c], w1 = lw[3*c+1], w2 = lw[3*c+2], lbc = lb[c];
        const bf16* vrow = kvbT + (size_t)(512 + c) * M_ + b * L_;
#pragma unroll
        for (int r = 0; r < 4; ++r) {
            const int n = tok + quad * 4 + r;
            const float v0 = (float)vrow[n];
            const float vm = (n > 0)      ? (float)vrow[n - 1] : 0.f;
            const float vp = (n < L_ - 1) ? (float)vrow[n + 1] : 0.f;
            const float lepe = vm * w0 + v0 * w1 + vp * w2 + lbc;
            const float xa = acc[ni][r] * zr[r] + lepe;
            const size_t off = ((size_t)b * L_ + n) * C_ + c;
            xa_mul[off] = (bf16)(xa * (float)act_res[off]);
        }
    }
}

// ---------------------------------------------------------------------------
// bf16 MFMA GEMM, m97 structure + XOR-swizzled LDS tiles (128x128, 4 waves).
// Kept for N=512 shapes (q, out-proj, fc2).
// R11: wide-store epilogue via wave-local LDS transpose (reuses As/Bs LDS
// after the final __syncthreads; per-wave disjoint scratch; no extra sync).
// EPI: 2 elu+1->bf16, 4 gelu->bf16, 5 +res->f32, 7 kvT (row<512 elu)->bf16,
//      8 fused act/in: col<512 silu->outp, else plain->outp2
// ---------------------------------------------------------------------------
template <int EPI>
__global__ __launch_bounds__(256) void gemm_bt(
    const bf16* __restrict__ A, const bf16* __restrict__ Bt,
    const float* __restrict__ bias, const float* __restrict__ res,
    void* __restrict__ outp, void* __restrict__ outp2, int K, int N)
{
    __shared__ bf16 smem[2 * 128 * 64];   // As | Bs (8192 each)
    bf16* As = smem;
    bf16* Bs = smem + 8192;
    const int tid = threadIdx.x;
    const int wave = tid >> 6, lane = tid & 63;
    const int wm = (wave & 1) * 64, wn = (wave >> 1) * 64;
    const int l16 = lane & 15, quad = lane >> 4;
    const size_t tileM = (size_t)blockIdx.x * 128;
    const size_t tileN = (size_t)blockIdx.y * 128;

    const int lrow = lane >> 3;
    const int lcol = (((lane & 7) ^ (lrow & 7))) * 8;   // swizzled source col
    const int swz  = l16 & 7;                           // read-side XOR

    const f32x4 z4 = { 0.f, 0.f, 0.f, 0.f };
    f32x4 acc[4][4];
#pragma unroll
    for (int mi = 0; mi < 4; ++mi)
#pragma unroll
        for (int ni = 0; ni < 4; ++ni) acc[mi][ni] = z4;

    for (int k0 = 0; k0 < K; k0 += 64) {
#pragma unroll
        for (int it = 0; it < 4; ++it) {
            const int rg = it * 32 + wave * 8;           // wave-uniform (mult of 8)
            load_lds16(A  + (tileM + rg + lrow) * (size_t)K + k0 + lcol, As + rg * 64);
            load_lds16(Bt + (tileN + rg + lrow) * (size_t)K + k0 + lcol, Bs + rg * 64);
        }
        __syncthreads();
#pragma unroll
        for (int kk = 0; kk < 64; kk += 32) {
            bf16x8 af[4], bfr[4];
#pragma unroll
            for (int mi = 0; mi < 4; ++mi)
                af[mi] = *(const bf16x8*)(&As[(wm + mi * 16 + l16) * 64
                                              + ((((kk >> 3) + quad) ^ swz) * 8)]);
#pragma unroll
            for (int ni = 0; ni < 4; ++ni)
                bfr[ni] = *(const bf16x8*)(&Bs[(wn + ni * 16 + l16) * 64
                                               + ((((kk >> 3) + quad) ^ swz) * 8)]);
#pragma unroll
            for (int mi = 0; mi < 4; ++mi)
#pragma unroll
                for (int ni = 0; ni < 4; ++ni)
                    acc[mi][ni] = __builtin_amdgcn_mfma_f32_16x16x32_bf16(
                        af[mi], bfr[ni], acc[mi][ni], 0, 0, 0);
        }
        __syncthreads();
    }

    // ---- R11 epilogue: wave-local LDS transpose -> coalesced wide stores.
    // All waves passed the final __syncthreads, so As/Bs LDS is reusable;
    // per-wave scratch regions are disjoint (same-wave LDS ops are in-order).
    const int rrow = lane >> 2;           // 0..15
    const int rseg = (lane & 3) * 16;     // 0/16/32/48

    if (EPI == 5 || EPI == 7) {
        float* sc = (float*)smem + wave * 1088;     // 16 rows x 68 f32
#pragma unroll
        for (int mi = 0; mi < 4; ++mi) {
#pragma unroll
            for (int ni = 0; ni < 4; ++ni)
#pragma unroll
                for (int r = 0; r < 4; ++r)
                    sc[(quad * 4 + r) * 68 + ni * 16 + l16] = acc[mi][ni][r];
            __builtin_amdgcn_sched_barrier(0);
            const size_t rowg = tileM + wm + mi * 16 + rrow;
            const int    colg = (int)tileN + wn + rseg;
            if (EPI == 5) {
                const float* rp = res + rowg * (size_t)N + colg;
                float*       op = (float*)outp + rowg * (size_t)N + colg;
#pragma unroll
                for (int u = 0; u < 4; ++u) {
                    f32x4 v = *(f32x4*)&sc[rrow * 68 + rseg + u * 4];
                    f32x4 rv = *(const f32x4*)(rp + u * 4);
                    f32x4 bv = *(const f32x4*)(bias + colg + u * 4);
                    f32x4 o;
#pragma unroll
                    for (int j = 0; j < 4; ++j) o[j] = v[j] + bv[j] + rv[j];
                    *(f32x4*)(op + u * 4) = o;
                }
            } else {  // EPI 7
                const float bv = bias[(int)rowg];
                const bool k_side = (rowg < 512);
                bf16* op = (bf16*)outp + rowg * (size_t)N + colg;
#pragma unroll
                for (int hh = 0; hh < 2; ++hh) {
                    bf16x8 o8;
#pragma unroll
                    for (int j = 0; j < 8; ++j) {
                        float x = sc[rrow * 68 + rseg + hh * 8 + j] + bv;
                        o8[j] = (bf16)(k_side ? elu1f(x) : x);
                    }
                    *(bf16x8*)(op + hh * 8) = o8;
                }
            }
            __builtin_amdgcn_sched_barrier(0);
        }
    } else {  // EPI 2, 4, 8: bf16 scratch, write-side bias+activation
        bf16* sc = (bf16*)smem + wave * 1152;       // 16 rows x 72 bf16
        float addc[4];
        bool  act_on[4];
#pragma unroll
        for (int ni = 0; ni < 4; ++ni) {
            const int cw = (int)tileN + wn + ni * 16 + l16;
            if (EPI == 8) {
                act_on[ni] = (cw < 512);
                addc[ni] = act_on[ni] ? bias[cw] : res[cw - 512];
            } else { addc[ni] = bias[cw]; act_on[ni] = true; }
        }
#pragma unroll
        for (int mi = 0; mi < 4; ++mi) {
#pragma unroll
            for (int ni = 0; ni < 4; ++ni)
#pragma unroll
                for (int r = 0; r < 4; ++r) {
                    float x = acc[mi][ni][r] + addc[ni];
                    float y;
                    if (EPI == 2)      y = elu1f(x);
                    else if (EPI == 4) y = geluf(x);
                    else               y = act_on[ni] ? siluf(x) : x;
                    sc[(quad * 4 + r) * 72 + ni * 16 + l16] = (bf16)y;
                }
            __builtin_amdgcn_sched_barrier(0);
            const size_t rowg = tileM + wm + mi * 16 + rrow;
            const int    colg = (int)tileN + wn + rseg;
            bf16x8 o0 = *(bf16x8*)&sc[rrow * 72 + rseg];
            bf16x8 o1 = *(bf16x8*)&sc[rrow * 72 + rseg + 8];
            if (EPI == 8) {
                const size_t orow = rowg * (size_t)512;
                bf16* dst = (colg < 512) ? ((bf16*)outp  + orow + colg)
                                         : ((bf16*)outp2 + orow + colg - 512);
                *(bf16x8*)dst = o0; *(bf16x8*)(dst + 8) = o1;
            } else {
                bf16* dst = (bf16*)outp + rowg * (size_t)N + colg;
                *(bf16x8*)dst = o0; *(bf16x8*)(dst + 8) = o1;
            }
            __builtin_amdgcn_sched_barrier(0);
        }
    }
}

// ---------------------------------------------------------------------------
// 256x256 8-wave (2M x 4N) deep-pipelined bf16 GEMM (R9 4-phase core). BK=64,
// double-buffered 128KB LDS, 4 phases per K-tile:
//   ph0: read A-half0(8) + B n0-1(4); stage next-tile loads 0-3;  MFMA m0-3 x n0-1
//   ph1: read B n2-3(4);              stage next-tile loads 4-7;  MFMA m0-3 x n2-3
//   ph2: read A-half1(8);                                         MFMA m4-7 x n0-1
//   ph3: vmcnt(0);                                                MFMA m4-7 x n2-3
// Each phase: raw s_barrier / lgkmcnt(0) / sched_barrier(0) / setprio(1) MFMA.
// R11: wide-store epilogue via wave-local LDS transpose.
// Requires: M % 256 == 0, N % 256 == 0, K % 64 == 0.
// ---------------------------------------------------------------------------
template <int EPI>
__global__ __launch_bounds__(512, 2) void gemm8(
    const bf16* __restrict__ A, const bf16* __restrict__ Bt,
    const float* __restrict__ bias, const float* __restrict__ res,
    void* __restrict__ outp, void* __restrict__ outp2, int K, int N)
{
    __shared__ bf16 smem[4 * 256 * 64];   // As[2] (32768) | Bs[2] (32768)
    bf16* const AsBase = smem;
    bf16* const BsBase = smem + 32768;
    const int tid  = threadIdx.x;
    const int wave = tid >> 6, lane = tid & 63;
    const int wrow = wave >> 2, wcol = wave & 3;       // 2 x 4 wave grid
    const int l16 = lane & 15, quad = lane >> 4;
    const int lrow = lane >> 3;                        // 0..7
    const int lcol = ((lane & 7) ^ lrow) * 8;          // swizzled source chunk
    const int swz  = l16 & 7;                          // read-side XOR
    const size_t tileM = (size_t)blockIdx.x * 256;
    const size_t tileN = (size_t)blockIdx.y * 256;

    // staging bases: wave w, load j covers rows j*64 + w*8 .. +7
    const bf16* aBase = A  + (tileM + wave * 8 + lrow) * (size_t)K + lcol;
    const bf16* bBase = Bt + (tileN + wave * 8 + lrow) * (size_t)K + lcol;
    const int ldsRow0 = wave * 8;

    f32x4 acc[8][4];
    const f32x4 z4 = { 0.f, 0.f, 0.f, 0.f };
#pragma unroll
    for (int mi = 0; mi < 8; ++mi)
#pragma unroll
        for (int ni = 0; ni < 4; ++ni) acc[mi][ni] = z4;

    // prologue: stage K-tile 0 into buf 0 (8 loads/thread), drain, barrier
#pragma unroll
    for (int j = 0; j < 4; ++j) {
        load_lds16(aBase + (size_t)(j * 64) * K, AsBase + (j * 64 + ldsRow0) * 64);
        load_lds16(bBase + (size_t)(j * 64) * K, BsBase + (j * 64 + ldsRow0) * 64);
    }
    asm volatile("s_waitcnt vmcnt(0)" ::: "memory");
    __builtin_amdgcn_s_barrier();

    const int T = K >> 6;
    int cur = 0;
    for (int t = 0; t < T; ++t) {
        const int nxt = cur ^ 1;
        const bool pf = (t + 1 < T);
        const int kc = (t + 1) << 6;                   // next tile's K offset
        const bf16* as = AsBase + cur * 16384;
        const bf16* bs = BsBase + cur * 16384;
        bf16* asn = AsBase + nxt * 16384;
        bf16* bsn = BsBase + nxt * 16384;
        bf16x8 af[4][2], bfr[4][2];

        // ---------------- phase 0: A-half0 + B(n0,n1); stage loads 0-3 ----
#pragma unroll
        for (int j = 0; j < 4; ++j)
#pragma unroll
            for (int kh = 0; kh < 2; ++kh)
                af[j][kh] = *(const bf16x8*)&as[(wrow * 128 + j * 16 + l16) * 64
                                               + (((kh * 4 + quad) ^ swz) * 8)];
#pragma unroll
        for (int ni = 0; ni < 2; ++ni)
#pragma unroll
            for (int kh = 0; kh < 2; ++kh)
                bfr[ni][kh] = *(const bf16x8*)&bs[(wcol * 64 + ni * 16 + l16) * 64
                                                  + (((kh * 4 + quad) ^ swz) * 8)];
        if (pf) {
#pragma unroll
            for (int j = 0; j < 2; ++j) {
                load_lds16(aBase + (size_t)(j * 64) * K + kc, asn + (j * 64 + ldsRow0) * 64);
                load_lds16(bBase + (size_t)(j * 64) * K + kc, bsn + (j * 64 + ldsRow0) * 64);
            }
        }
        __builtin_amdgcn_s_barrier();
        asm volatile("s_waitcnt lgkmcnt(0)" ::: "memory");
        __builtin_amdgcn_sched_barrier(0);
        __builtin_amdgcn_s_setprio(1);
#pragma unroll
        for (int j = 0; j < 4; ++j)
#pragma unroll
            for (int ni = 0; ni < 2; ++ni)
#pragma unroll
                for (int kh = 0; kh < 2; ++kh)
                    acc[j][ni] = __builtin_amdgcn_mfma_f32_16x16x32_bf16(
                        af[j][kh], bfr[ni][kh], acc[j][ni], 0, 0, 0);
        __builtin_amdgcn_s_setprio(0);
        __builtin_amdgcn_s_barrier();

        // ---------------- phase 1: B(n2,n3); stage loads 4-7 --------------
#pragma unroll
        for (int ni = 2; ni < 4; ++ni)
#pragma unroll
            for (int kh = 0; kh < 2; ++kh)
                bfr[ni][kh] = *(const bf16x8*)&bs[(wcol * 64 + ni * 16 + l16) * 64
                                                  + (((kh * 4 + quad) ^ swz) * 8)];
        if (pf) {
#pragma unroll
            for (int j = 2; j < 4; ++j) {
                load_lds16(aBase + (size_t)(j * 64) * K + kc, asn + (j * 64 + ldsRow0) * 64);
                load_lds16(bBase + (size_t)(j * 64) * K + kc, bsn + (j * 64 + ldsRow0) * 64);
            }
        }
        __builtin_amdgcn_s_barrier();
        asm volatile("s_waitcnt lgkmcnt(0)" ::: "memory");
        __builtin_amdgcn_sched_barrier(0);
        __builtin_amdgcn_s_setprio(1);
#pragma unroll
        for (int j = 0; j < 4; ++j)
#pragma unroll
            for (int ni = 2; ni < 4; ++ni)
#pragma unroll
                for (int kh = 0; kh < 2; ++kh)
                    acc[j][ni] = __builtin_amdgcn_mfma_f32_16x16x32_bf16(
                        af[j][kh], bfr[ni][kh], acc[j][ni], 0, 0, 0);
        __builtin_amdgcn_s_setprio(0);
        __builtin_amdgcn_s_barrier();

        // ---------------- phase 2: A-half1 --------------------------------
#pragma unroll
        for (int j = 0; j < 4; ++j)
#pragma unroll
            for (int kh = 0; kh < 2; ++kh)
                af[j][kh] = *(const bf16x8*)&as[(wrow * 128 + 64 + j * 16 + l16) * 64
                                               + (((kh * 4 + quad) ^ swz) * 8)];
        __builtin_amdgcn_s_barrier();
        asm volatile("s_waitcnt lgkmcnt(0)" ::: "memory");
        __builtin_amdgcn_sched_barrier(0);
        __builtin_amdgcn_s_setprio(1);
#pragma unroll
        for (int j = 0; j < 4; ++j)
#pragma unroll
            for (int ni = 0; ni < 2; ++ni)
#pragma unroll
                for (int kh = 0; kh < 2; ++kh)
                    acc[4 + j][ni] = __builtin_amdgcn_mfma_f32_16x16x32_bf16(
                        af[j][kh], bfr[ni][kh], acc[4 + j][ni], 0, 0, 0);
        __builtin_amdgcn_s_setprio(0);
        __builtin_amdgcn_s_barrier();

        // ---------------- phase 3: wait next tile; last quadrant ----------
        if (pf) asm volatile("s_waitcnt vmcnt(0)" ::: "memory");
        __builtin_amdgcn_s_barrier();
        __builtin_amdgcn_sched_barrier(0);
        __builtin_amdgcn_s_setprio(1);
#pragma unroll
        for (int j = 0; j < 4; ++j)
#pragma unroll
            for (int ni = 2; ni < 4; ++ni)
#pragma unroll
                for (int kh = 0; kh < 2; ++kh)
                    acc[4 + j][ni] = __builtin_amdgcn_mfma_f32_16x16x32_bf16(
                        af[j][kh], bfr[ni][kh], acc[4 + j][ni], 0, 0, 0);
        __builtin_amdgcn_s_setprio(0);
        __builtin_amdgcn_s_barrier();

        cur = nxt;
    }

    // ---- R11 epilogue: wave-local LDS transpose -> coalesced wide stores.
    // Loop ended with s_barrier: all waves done reading As/Bs; vmcnt drained.
    const int rrow = lane >> 2;           // 0..15
    const int rseg = (lane & 3) * 16;     // 0/16/32/48

    if (EPI == 5 || EPI == 7) {
        float* sc = (float*)smem + wave * 1088;     // 16 rows x 68 f32
#pragma unroll
        for (int mi = 0; mi < 8; ++mi) {
#pragma unroll
            for (int ni = 0; ni < 4; ++ni)
#pragma unroll
                for (int r = 0; r < 4; ++r)
                    sc[(quad * 4 + r) * 68 + ni * 16 + l16] = acc[mi][ni][r];
            __builtin_amdgcn_sched_barrier(0);
            const size_t rowg = tileM + wrow * 128 + mi * 16 + rrow;
            const int    colg = (int)tileN + wcol * 64 + rseg;
            if (EPI == 5) {
                const float* rp = res + rowg * (size_t)N + colg;
                float*       op = (float*)outp + rowg * (size_t)N + colg;
#pragma unroll
                for (int u = 0; u < 4; ++u) {
                    f32x4 v = *(f32x4*)&sc[rrow * 68 + rseg + u * 4];
                    f32x4 rv = *(const f32x4*)(rp + u * 4);
                    f32x4 bv = *(const f32x4*)(bias + colg + u * 4);
                    f32x4 o;
#pragma unroll
                    for (int j = 0; j < 4; ++j) o[j] = v[j] + bv[j] + rv[j];
                    *(f32x4*)(op + u * 4) = o;
                }
            } else {  // EPI 7
                const float bv = bias[(int)rowg];
                const bool k_side = (rowg < 512);
                bf16* op = (bf16*)outp + rowg * (size_t)N + colg;
#pragma unroll
                for (int hh = 0; hh < 2; ++hh) {
                    bf16x8 o8;
#pragma unroll
                    for (int j = 0; j < 8; ++j) {
                        float x = sc[rrow * 68 + rseg + hh * 8 + j] + bv;
                        o8[j] = (bf16)(k_side ? elu1f(x) : x);
                    }
                    *(bf16x8*)(op + hh * 8) = o8;
                }
            }
            __builtin_amdgcn_sched_barrier(0);
        }
    } else {  // EPI 2, 4, 8: bf16 scratch, write-side bias+activation
        bf16* sc = (bf16*)smem + wave * 1152;       // 16 rows x 72 bf16
        float addc[4];
        bool  act_on[4];
#pragma unroll
        for (int ni = 0; ni < 4; ++ni) {
            const int cw = (int)tileN + wcol * 64 + ni * 16 + l16;
            if (EPI == 8) {
                act_on[ni] = (cw < 512);
                addc[ni] = act_on[ni] ? bias[cw] : res[cw - 512];
            } else { addc[ni] = bias[cw]; act_on[ni] = true; }
        }
#pragma unroll
        for (int mi = 0; mi < 8; ++mi) {
#pragma unroll
            for (int ni = 0; ni < 4; ++ni)
#pragma unroll
                for (int r = 0; r < 4; ++r) {
                    float x = acc[mi][ni][r] + addc[ni];
                    float y;
                    if (EPI == 2)      y = elu1f(x);
                    else if (EPI == 4) y = geluf(x);
                    else               y = act_on[ni] ? siluf(x) : x;
                    sc[(quad * 4 + r) * 72 + ni * 16 + l16] = (bf16)y;
                }
            __builtin_amdgcn_sched_barrier(0);
            const size_t rowg = tileM + wrow * 128 + mi * 16 + rrow;
            const int    colg = (int)tileN + wcol * 64 + rseg;
            bf16x8 o0 = *(bf16x8*)&sc[rrow * 72 + rseg];
            bf16x8 o1 = *(bf16x8*)&sc[rrow * 72 + rseg + 8];
            if (EPI == 8) {
                const size_t orow = rowg * (size_t)512;
                bf16* dst = (colg < 512) ? ((bf16*)outp  + orow + colg)
                                         : ((bf16*)outp2 + orow + colg - 512);
                *(bf16x8*)dst = o0; *(bf16x8*)(dst + 8) = o1;
            } else {
                bf16* dst = (bf16*)outp + rowg * (size_t)N + colg;
                *(bf16x8*)dst = o0; *(bf16x8*)(dst + 8) = o1;
            }
            __builtin_amdgcn_sched_barrier(0);
        }
    }
}

// ---------------------------------------------------------------------------
// workspace layout (bytes) — total 125,845,504 (~120 MiB)
// ---------------------------------------------------------------------------
#define OFF_WT_ACTIN ((size_t)0)         // bf16 [1024][512] 1MB
#define OFF_WT_Q    ((size_t)1048576)
#define OFF_WT_KV   ((size_t)1572864)
#define OFF_WT_OUT  ((size_t)2621440)
#define OFF_WT_FC1  ((size_t)3145728)
#define OFF_WT_FC2  ((size_t)5242880)
#define OFF_XLN     ((size_t)7340032)    // bf16 16MB (xqb, kvbf, hln alias)
#define OFF_ACTRES  ((size_t)24117248)   // bf16 16MB (x3 aliases from here)
#define OFF_Y       ((size_t)40894464)   // bf16 16MB (qb aliases)
#define OFF_XP      ((size_t)57671680)   // bf16 16MB (kvpart, h1 alias from here)
#define OFF_KV      ((size_t)74448896)   // bf16 32MB  kvbT [1024][16384]
#define OFF_KSUM    ((size_t)108003328)  // f32 16KB
#define OFF_XAMUL   ((size_t)109068288)  // bf16 16MB  -> end 125845504
#define OFF_X3      ((size_t)24117248)   // f32 32MB over actres+Y (dead)
#define OFF_H1      ((size_t)57671680)   // bf16 64MB over xp+kv+xamul (dead)
#define WS_REQUIRED ((size_t)125845504)

extern "C" void kernel_launch(void* const* d_in, const int* in_sizes, int n_in,
                              void* d_out, int out_size, void* d_ws, size_t ws_size,
                              hipStream_t stream)
{
    const float* x_q    = (const float*)d_in[0];
    const float* x_kv   = (const float*)d_in[1];
    const float* cpe1_w = (const float*)d_in[2];
    const float* cpe1_b = (const float*)d_in[3];
    const float* n1_g   = (const float*)d_in[4];
    const float* n1_b   = (const float*)d_in[5];
    const float* in_w   = (const float*)d_in[6];
    const float* in_b   = (const float*)d_in[7];
    const float* act_w  = (const float*)d_in[8];
    const float* act_b  = (const float*)d_in[9];
    const float* dwc_w  = (const float*)d_in[10];
    const float* dwc_b  = (const float*)d_in[11];
    const float* q_w    = (const float*)d_in[12];
    const float* q_b    = (const float*)d_in[13];
    const float* kv_w   = (const float*)d_in[14];
    const float* kv_b   = (const float*)d_in[15];
    const float* lepe_w = (const float*)d_in[16];
    const float* lepe_b = (const float*)d_in[17];
    const float* out_w  = (const float*)d_in[18];
    const float* out_b  = (const float*)d_in[19];
    const float* cpe2_w = (const float*)d_in[20];
    const float* cpe2_b = (const float*)d_in[21];
    const float* n2_g   = (const float*)d_in[22];
    const float* n2_b   = (const float*)d_in[23];
    const float* fc1_w  = (const float*)d_in[24];
    const float* fc1_b  = (const float*)d_in[25];
    const float* fc2_w  = (const float*)d_in[26];
    const float* fc2_b  = (const float*)d_in[27];

    float* outf = (float*)d_out;

    if (ws_size < WS_REQUIRED) {
        zero_k<<<(out_size + 255) / 256, 256, 0, stream>>>(outf, out_size);
        ws_diag_k<<<1, 64, 0, stream>>>(outf, (float)ws_size);
        return;
    }

    char* ws = (char*)d_ws;
    bf16*  wt_actin = (bf16*)(ws + OFF_WT_ACTIN);
    bf16*  wt_q   = (bf16*)(ws + OFF_WT_Q);
    bf16*  wt_kv  = (bf16*)(ws + OFF_WT_KV);
    bf16*  wt_out = (bf16*)(ws + OFF_WT_OUT);
    bf16*  wt_fc1 = (bf16*)(ws + OFF_WT_FC1);
    bf16*  wt_fc2 = (bf16*)(ws + OFF_WT_FC2);
    bf16*  xln    = (bf16*)(ws + OFF_XLN);
    bf16*  xqb    = (bf16*)(ws + OFF_XLN);      // alias: xln dead after act/in
    bf16*  kvbf   = (bf16*)(ws + OFF_XLN);      // alias: xqb dead after q-gemm
    bf16*  hln    = (bf16*)(ws + OFF_XLN);      // alias: kvbf dead after attn
    bf16*  actres = (bf16*)(ws + OFF_ACTRES);
    bf16*  Y      = (bf16*)(ws + OFF_Y);
    bf16*  qb     = (bf16*)(ws + OFF_Y);        // alias: Y dead after dwc
    bf16*  xp     = (bf16*)(ws + OFF_XP);
    float* kvpart = (float*)(ws + OFF_XP);      // alias: xp dead after kv-gemm (4MB)
    bf16*  kvbT   = (bf16*)(ws + OFF_KV);       // [1024][16384]
    float* ksum   = (float*)(ws + OFF_KSUM);
    bf16*  xamul  = (bf16*)(ws + OFF_XAMUL);
    float* x3     = (float*)(ws + OFF_X3);      // alias
    bf16*  h1     = (bf16*)(ws + OFF_H1);       // alias

    // all weight transposes in one launch
    TJobs jobs;
    jobs.j[0] = { act_w, wt_actin,             512,  512,    0 };
    jobs.j[1] = { in_w,  wt_actin + 512 * 512, 512,  512,  256 };
    jobs.j[2] = { q_w,   wt_q,                 512,  512,  512 };
    jobs.j[3] = { kv_w,  wt_kv,                512, 1024,  768 };
    jobs.j[4] = { out_w, wt_out,               512,  512, 1280 };
    jobs.j[5] = { fc1_w, wt_fc1,               512, 2048, 1536 };
    jobs.j[6] = { fc2_w, wt_fc2,              2048,  512, 2560 };
    transpose_all_k<<<3584, 256, 0, stream>>>(jobs);

    // cpe1 + LN1: shortcut (fp32) lives in d_out
    cpe_ln_k<<<M_, 256, 0, stream>>>(x_kv, cpe1_w, cpe1_b, n1_g, n1_b, outf, xln);

    // fused act gate + in-proj (one pass over xln), N=1024  [256x256 pipelined]
    gemm8<8><<<dim3(64, 4), 512, 0, stream>>>(xln, wt_actin, act_b, in_b, actres, Y, 512, 1024);

    // flat-reshape dwconv + silu -> xp (frees Y)
    dwc_silu_k<<<32768, 256, 0, stream>>>(Y, dwc_w, dwc_b, xp);

    // x_q -> bf16 (into dead xln region), then q = elu+1(xqb @ q_w) -> qb (@Y)
    f32_to_bf16_k<<<8192, 256, 0, stream>>>(x_q, xqb, M_ * C_ / 4);
    gemm_bt<2><<<dim3(128, 4), 256, 0, stream>>>(xqb, wt_q, q_b, nullptr, qb, nullptr, 512, 512);

    // kvbT[c][token] = (xp @ kv_w)^T : roles swapped (A=wt_kv, Bt=xp)  [256x256]
    gemm8<7><<<dim3(4, 64), 512, 0, stream>>>(wt_kv, xp, kv_b, nullptr, kvbT, nullptr, 512, M_);

    // k_mean, kvmatT partials (MFMA, no atomics), reduce+bf16 convert
    ksum_k<<<C_, 256, 0, stream>>>(kvbT, ksum);
    kvmat_mfma_k<<<dim3(64, 4), 256, 0, stream>>>(kvbT, kvpart);
    kvconv_k<<<1024, 256, 0, stream>>>(kvpart, kvbf);

    // MFMA attention + lepe + gate multiply
    attn_mfma_k<<<dim3(64, 32), 256, 0, stream>>>(qb, kvbT, kvbf, ksum,
                                                  lepe_w, lepe_b, actres, xamul);

    // out-proj + shortcut residual, in-place on d_out
    gemm_bt<5><<<dim3(128, 4), 256, 0, stream>>>(xamul, wt_out, out_b, outf, outf, nullptr, 512, 512);

    // cpe2 + LN2: x2 (=d_out) -> x3 (fp32 ws) + hln (bf16)
    cpe_ln_k<<<M_, 256, 0, stream>>>(outf, cpe2_w, cpe2_b, n2_g, n2_b, x3, hln);

    // MLP: fc1 (gelu) [256x256 pipelined] -> fc2 (+x3) -> d_out
    gemm8<4><<<dim3(64, 8), 512, 0, stream>>>(hln, wt_fc1, fc1_b, nullptr, h1, nullptr, 512, 2048);
    gemm_bt<5><<<dim3(128, 4),  256, 0, stream>>>(h1,  wt_fc2, fc2_b, x3, outf, nullptr, 2048, 512);

    (void)in_sizes; (void)n_in; (void)out_size; (void)ws_size;
}